// Round 14
// baseline (299.786 us; speedup 1.0000x reference)
//
#include <hip/hip_runtime.h>
#include <cstdint>

// WeightedPolynormerGlobal: B=8, NMAX=8192, D=256, H=8, DH=32, rows N=65536.
// Pipeline: prep+LN1 -> fused GEMM (h|q|k|v) -> kv/ksum reduce -> fused
//           attn+LN2+outGEMM (z never hits HBM).
// R5: gemm structure (BK=32, 4 blocks/CU, staged epilogue) -> gemm0 81us.
// R12: kvred per-wave chunks + 4x4 register blocking.
// R13: fused attnz+gemm1 (attout_k), z in swizzled LDS. Total 196.5us.
// R14: attout phase-1 rework — wave-independent 8-row passes (private q_s via
//      gload_lds + per-wave drain, ZERO barriers in phase 1), dl-outer loop
//      (kvv amortized over 8 rows), ksum in registers. LDS exactly 80KB.

#define DEVI __device__ __forceinline__

typedef __attribute__((ext_vector_type(8))) short bf16x8;   // 8 bf16 in 4 VGPRs
typedef __attribute__((ext_vector_type(4))) float f32x4;

DEVI ushort f2bf(float f) {  // RNE float->bf16
  uint32_t u = __float_as_uint(f);
  u += 0x7FFFu + ((u >> 16) & 1u);
  return (ushort)(u >> 16);
}
DEVI float bf2f(ushort h) { return __uint_as_float(((uint32_t)h) << 16); }

DEVI void gload_lds16(const void* g, void* l) {
  __builtin_amdgcn_global_load_lds((const __attribute__((address_space(1))) void*)g,
                                   (__attribute__((address_space(3))) void*)l, 16, 0, 0);
}
DEVI void vm_drain() { asm volatile("s_waitcnt vmcnt(0)" ::: "memory"); }

// ---------------- K1: prep (weights->bf16 transposed, zero accum) + LN1 ------
__global__ __launch_bounds__(256)
void ln1_k(const float* __restrict__ x, const float* __restrict__ g1,
           const float* __restrict__ b1, ushort* __restrict__ x0b,
           const float* __restrict__ Wh, const float* __restrict__ Wq,
           const float* __restrict__ Wk, const float* __restrict__ Wv,
           const float* __restrict__ Wout,
           const float* __restrict__ bh, const float* __restrict__ bq,
           const float* __restrict__ bk, const float* __restrict__ bv,
           ushort* __restrict__ Wcat_t, ushort* __restrict__ Woutt,
           float* __restrict__ bcat, float* __restrict__ kv, float* __restrict__ ksum)
{
  const int t = threadIdx.x;
  const int idx = blockIdx.x * 256 + t;
  if (idx < 396288) {
    if (idx < 262144) {                       // Wcat_t[j][kk] = W_g[kk][jj]
      int j = idx >> 8, kk = idx & 255;
      int g = j >> 8, jj = j & 255;
      const float* W = (g == 0) ? Wh : (g == 1) ? Wq : (g == 2) ? Wk : Wv;
      Wcat_t[idx] = f2bf(W[kk * 256 + jj]);
    }
    int i2 = idx - 262144;
    if (i2 >= 0 && i2 < 65536) {              // Woutt[j][kk] = Wout[kk][j]
      int j = i2 >> 8, kk = i2 & 255;
      Woutt[i2] = f2bf(Wout[kk * 256 + j]);
    }
    int i3 = idx - (262144 + 65536);
    if (i3 >= 0 && i3 < 1024) {
      int g = i3 >> 8, jj = i3 & 255;
      const float* bb = (g == 0) ? bh : (g == 1) ? bq : (g == 2) ? bk : bv;
      bcat[i3] = bb[jj];
    }
    int i4 = idx - (262144 + 65536 + 1024);
    if (i4 >= 0 && i4 < 65536) kv[i4] = 0.0f;
    int i5 = idx - (262144 + 65536 + 1024 + 65536);
    if (i5 >= 0 && i5 < 2048) ksum[i5] = 0.0f;
  }
  const int l = t & 63, w = t >> 6;
  const size_t r = (size_t)blockIdx.x * 4 + w;
  const float4 xv = *(const float4*)&x[r * 256 + l * 4];
  float s = xv.x + xv.y + xv.z + xv.w;
  float sq = xv.x * xv.x + xv.y * xv.y + xv.z * xv.z + xv.w * xv.w;
#pragma unroll
  for (int off = 1; off < 64; off <<= 1) { s += __shfl_xor(s, off); sq += __shfl_xor(sq, off); }
  const float mean = s * (1.0f / 256.0f);
  const float var = sq * (1.0f / 256.0f) - mean * mean;
  const float rstd = rsqrtf(var + 1e-5f);
  const float4 g4 = *(const float4*)&g1[l * 4];
  const float4 b4 = *(const float4*)&b1[l * 4];
  ushort4 o;
  o.x = f2bf((xv.x - mean) * rstd * g4.x + b4.x);
  o.y = f2bf((xv.y - mean) * rstd * g4.y + b4.y);
  o.z = f2bf((xv.z - mean) * rstd * g4.z + b4.z);
  o.w = f2bf((xv.w - mean) * rstd * g4.w + b4.w);
  *(ushort4*)&x0b[r * 256 + l * 4] = o;
}

// ---------------- K2: bf16 MFMA GEMM (h|q|k|v), 128x128 tile, BK=32 ----------
template <int MODE>
__global__ __launch_bounds__(256, 4)
void gemm_bf16_k(const ushort* __restrict__ A, const ushort* __restrict__ Bt,
                 const float* __restrict__ bias, const float* __restrict__ node_prob,
                 const ushort* __restrict__ x0b, ushort* __restrict__ outb,
                 float* __restrict__ outf)
{
  __shared__ ushort smem[16384];               // 32 KB
  const int t = threadIdx.x;
  const int l = t & 63;
  const int w = t >> 6;
  const int wr = w >> 1, wc = w & 1;           // 2x2 waves of 64x64
  const int nNB = (MODE == 0) ? 8 : 2;
  const int per = gridDim.x >> 3;
  const int tile = (blockIdx.x & 7) * per + (blockIdx.x >> 3);
  const int m0 = (tile / nNB) * 128, n0 = (tile % nNB) * 128;
  const int sr = t >> 2;
  const int sd = t & 3;
  const int ssl = sd ^ ((t >> 3) & 3);         // pre-swizzled global src slot
  f32x4 acc[4][4] = {};

  auto stage = [&](int buf, int kt) {
#pragma unroll
    for (int i = 0; i < 2; ++i) {
      int row = i * 64 + sr;
      gload_lds16(&A[(size_t)(m0 + row) * 256 + kt * 32 + ssl * 8],
                  &smem[buf * 4096 + row * 32 + sd * 8]);
    }
#pragma unroll
    for (int i = 0; i < 2; ++i) {
      int row = i * 64 + sr;
      gload_lds16(&Bt[(size_t)(n0 + row) * 256 + kt * 32 + ssl * 8],
                  &smem[8192 + buf * 4096 + row * 32 + sd * 8]);
    }
  };

  stage(0, 0);
  vm_drain();
  __syncthreads();
  const int fr = l & 15;
  const int fq = l >> 4;
  const int fsl = (fq ^ ((l >> 1) & 3)) * 8;
#pragma unroll
  for (int kt = 0; kt < 8; ++kt) {
    const int cur = kt & 1;
    if (kt < 7) stage(cur ^ 1, kt + 1);
    bf16x8 af[4], bfr[4];
#pragma unroll
    for (int f = 0; f < 4; ++f) {
      af[f]  = *(const bf16x8*)&smem[cur * 4096 + (wr * 64 + f * 16 + fr) * 32 + fsl];
      bfr[f] = *(const bf16x8*)&smem[8192 + cur * 4096 + (wc * 64 + f * 16 + fr) * 32 + fsl];
    }
#pragma unroll
    for (int fm = 0; fm < 4; ++fm)
#pragma unroll
      for (int fn = 0; fn < 4; ++fn)
        acc[fm][fn] = __builtin_amdgcn_mfma_f32_16x16x32_bf16(af[fm], bfr[fn], acc[fm][fn], 0, 0, 0);
    vm_drain();
    __syncthreads();
  }

  float biasv[4];
#pragma unroll
  for (int fn = 0; fn < 4; ++fn) biasv[fn] = bias[n0 + wc * 64 + fn * 16 + fr];
  const int g = n0 >> 8;
#pragma unroll
  for (int fm = 0; fm < 4; ++fm) {
#pragma unroll
    for (int fn = 0; fn < 4; ++fn) {
#pragma unroll
      for (int i = 0; i < 4; ++i) {
        const int row = wr * 64 + fm * 16 + fq * 4 + i;
        const int col = wc * 64 + fn * 16 + fr;
        float v = acc[fm][fn][i] + biasv[fn];
        if (MODE == 0) {
          if (g == 1 || g == 2) v = 1.0f / (1.0f + __expf(-v));
          if (g == 2) v *= node_prob[m0 + row];
        } else {
          v = fmaxf(v, 0.0f);
        }
        smem[row * 128 + (col ^ ((row & 7) << 4))] = f2bf(v);
      }
    }
  }
  __syncthreads();
#pragma unroll
  for (int it = 0; it < 8; ++it) {
    const int row = w * 32 + it * 4 + fq;
    const int c8 = fr * 8;
    bf16x8 u = *(const bf16x8*)&smem[row * 128 + (c8 ^ ((row & 7) << 4))];
    if (MODE == 0) {
      *(bf16x8*)&outb[(size_t)(m0 + row) * 1024 + n0 + c8] = u;
    } else {
      bf16x8 xv = *(const bf16x8*)&x0b[(size_t)(m0 + row) * 256 + n0 + c8];
      float4 o0, o1;
      o0.x = bf2f((ushort)u[0]) + bf2f((ushort)xv[0]);
      o0.y = bf2f((ushort)u[1]) + bf2f((ushort)xv[1]);
      o0.z = bf2f((ushort)u[2]) + bf2f((ushort)xv[2]);
      o0.w = bf2f((ushort)u[3]) + bf2f((ushort)xv[3]);
      o1.x = bf2f((ushort)u[4]) + bf2f((ushort)xv[4]);
      o1.y = bf2f((ushort)u[5]) + bf2f((ushort)xv[5]);
      o1.z = bf2f((ushort)u[6]) + bf2f((ushort)xv[6]);
      o1.w = bf2f((ushort)u[7]) + bf2f((ushort)xv[7]);
      *(float4*)&outf[(size_t)(m0 + row) * 256 + n0 + c8] = o0;
      *(float4*)&outf[(size_t)(m0 + row) * 256 + n0 + c8 + 4] = o1;
    }
  }
}

// ---------------- K3: kv/ksum reduce (R12: per-wave chunks, 4x4 reg block) ---
__global__ __launch_bounds__(256)
void kvred_k(const ushort* __restrict__ hqkv, float* __restrict__ kv, float* __restrict__ ksum)
{
  __shared__ ushort smem[32768];               // 64KB: wave w: k @ w*8192, v @ +4096
  const int t = threadIdx.x, l = t & 63, w = t >> 6;
  const int bh = blockIdx.x >> 4, cb = blockIdx.x & 15;
  const int b = bh >> 3, h = bh & 7;
  const size_t nbase = (size_t)b * 8192 + cb * 512 + w * 128;
  ushort* kt = &smem[w * 8192];
  ushort* vt = &smem[w * 8192 + 4096];
#pragma unroll
  for (int i = 0; i < 8; ++i) {
    size_t row = nbase + i * 16 + (l >> 2);
    gload_lds16(&hqkv[row * 1024 + 512 + h * 32 + (l & 3) * 8], &kt[i * 512 + l * 8]);
  }
#pragma unroll
  for (int i = 0; i < 8; ++i) {
    size_t row = nbase + i * 16 + (l >> 2);
    gload_lds16(&hqkv[row * 1024 + 768 + h * 32 + (l & 3) * 8], &vt[i * 512 + l * 8]);
  }
  vm_drain();

  const int d0 = (l & 7) * 4, e0 = (l >> 3) * 4;
  float acc[4][4] = {};
  float ks0 = 0, ks1 = 0, ks2 = 0, ks3 = 0;
#pragma unroll 8
  for (int nn = 0; nn < 128; ++nn) {
    ushort4 kk = *(const ushort4*)&kt[nn * 32 + d0];
    ushort4 vv = *(const ushort4*)&vt[nn * 32 + e0];
    float k0 = bf2f(kk.x), k1 = bf2f(kk.y), k2 = bf2f(kk.z), k3 = bf2f(kk.w);
    float v0 = bf2f(vv.x), v1 = bf2f(vv.y), v2 = bf2f(vv.z), v3 = bf2f(vv.w);
    acc[0][0] += k0 * v0; acc[0][1] += k0 * v1; acc[0][2] += k0 * v2; acc[0][3] += k0 * v3;
    acc[1][0] += k1 * v0; acc[1][1] += k1 * v1; acc[1][2] += k1 * v2; acc[1][3] += k1 * v3;
    acc[2][0] += k2 * v0; acc[2][1] += k2 * v1; acc[2][2] += k2 * v2; acc[2][3] += k2 * v3;
    acc[3][0] += k3 * v0; acc[3][1] += k3 * v1; acc[3][2] += k3 * v2; acc[3][3] += k3 * v3;
    ks0 += k0; ks1 += k1; ks2 += k2; ks3 += k3;
  }
  __syncthreads();
  float* part = (float*)(void*)smem;
#pragma unroll
  for (int dd = 0; dd < 4; ++dd)
#pragma unroll
    for (int ee = 0; ee < 4; ++ee)
      part[w * 1024 + (dd * 4 + ee) * 64 + l] = acc[dd][ee];
  if (l < 8) {
    part[4096 + w * 32 + l * 4 + 0] = ks0;
    part[4096 + w * 32 + l * 4 + 1] = ks1;
    part[4096 + w * 32 + l * 4 + 2] = ks2;
    part[4096 + w * 32 + l * 4 + 3] = ks3;
  }
  __syncthreads();
  const int lsrc = t & 63;
#pragma unroll
  for (int j = 0; j < 4; ++j) {
    const int val = (t >> 6) * 4 + j;
    float s = part[0 * 1024 + val * 64 + lsrc] + part[1 * 1024 + val * 64 + lsrc]
            + part[2 * 1024 + val * 64 + lsrc] + part[3 * 1024 + val * 64 + lsrc];
    const int d = (lsrc & 7) * 4 + (val >> 2);
    const int e = (lsrc >> 3) * 4 + (val & 3);
    atomicAdd(&kv[(size_t)bh * 1024 + d * 32 + e], s);
  }
  if (t < 32) {
    float s = part[4096 + t] + part[4096 + 32 + t] + part[4096 + 64 + t] + part[4096 + 96 + t];
    atomicAdd(&ksum[bh * 32 + t], s);
  }
}

// ---------------- K4: FUSED attn+LN2+outGEMM ---------------------------------
// 64 rows/block, 1024 blocks. LDS exactly 80KB (2 blocks/CU):
//   [0,32KB): kv_s f32 (phase1) / Woutt dbuf Bst (phase2)
//   [32KB,48KB): q_s — wave-private 8-row slices (4KB/wave), restaged per pass
//   [48KB,80KB): z_s bf16 64x256, slot-swizzled phys = slot ^ (row&15)
// Phase1 (barrier-free): wave w owns rows w*16..+15, two 8-row passes;
//   dl-outer loop amortizes kvv over 8 rows; ksum in registers.
// Phase2: gemm1 K-loop, A from z tile, relu+bout+x0 residual, f32 stores.
__global__ __launch_bounds__(256, 2)
void attout_k(const ushort* __restrict__ hqkv, const float* __restrict__ kv,
              const float* __restrict__ ksum, const float* __restrict__ g2,
              const float* __restrict__ b2, const float* __restrict__ beta,
              const ushort* __restrict__ Woutt, const float* __restrict__ bout,
              const ushort* __restrict__ x0b, float* __restrict__ out)
{
  __shared__ ushort smem[40960];               // 80 KB exactly
  float* kv_s = (float*)(void*)smem;           // 8192 f32
  ushort* q_s = smem + 16384;                  // [w][8][256] per pass
  ushort* z_s = smem + 24576;                  // 64x256 bf16 (swizzled)

  const int t = threadIdx.x, l = t & 63, w = t >> 6;
  const int r0 = blockIdx.x * 64;
  const int b = r0 >> 13;
  const int h = l >> 3, e0 = (l & 7) * 4;

  // ksum -> registers (lane's head only; L2-hot)
  float4 ksr[8];
#pragma unroll
  for (int i = 0; i < 8; ++i)
    ksr[i] = *(const float4*)&ksum[(b * 8 + h) * 32 + i * 4];

#pragma unroll
  for (int i = 0; i < 8; ++i)
    *(float4*)&kv_s[i * 1024 + t * 4] = *(const float4*)&kv[(size_t)b * 8192 + i * 1024 + t * 4];
  __syncthreads();                             // kv_s published

  const float4 g4 = *(const float4*)&g2[l * 4];
  const float4 bb4 = *(const float4*)&b2[l * 4];
  const float4 be4 = *(const float4*)&beta[l * 4];

  for (int p = 0; p < 2; ++p) {                // two 8-row passes, barrier-free
    // stage wave's 8 q rows into private q_s slice (linear dest, per-wave drain)
#pragma unroll
    for (int i = 0; i < 4; ++i) {
      int row = p * 8 + i * 2 + (l >> 5);      // row within wave's 16
      gload_lds16(&hqkv[(size_t)(r0 + w * 16 + row) * 1024 + 256 + (l & 31) * 8],
                  &q_s[w * 2048 + i * 512 + l * 8]);
    }
    vm_drain();                                // private slice ready (this wave only)

    float num[8][4] = {};
    float den[8] = {0, 0, 0, 0, 0, 0, 0, 0};
#pragma unroll
    for (int dl = 0; dl < 8; ++dl) {
      const float4 ks4 = ksr[dl];
      float4 kvv[4];
#pragma unroll
      for (int c = 0; c < 4; ++c)
        kvv[c] = *(const float4*)&kv_s[h * 1024 + (dl * 4 + c) * 32 + e0];
#pragma unroll
      for (int rr = 0; rr < 8; ++rr) {
        ushort4 qv = *(const ushort4*)&q_s[w * 2048 + rr * 256 + h * 32 + dl * 4];
        float qx = bf2f(qv.x), qy = bf2f(qv.y), qz = bf2f(qv.z), qw = bf2f(qv.w);
        den[rr] += qx * ks4.x + qy * ks4.y + qz * ks4.z + qw * ks4.w;
        num[rr][0] += qx * kvv[0].x + qy * kvv[1].x + qz * kvv[2].x + qw * kvv[3].x;
        num[rr][1] += qx * kvv[0].y + qy * kvv[1].y + qz * kvv[2].y + qw * kvv[3].y;
        num[rr][2] += qx * kvv[0].z + qy * kvv[1].z + qz * kvv[2].z + qw * kvv[3].z;
        num[rr][3] += qx * kvv[0].w + qy * kvv[1].w + qz * kvv[2].w + qw * kvv[3].w;
      }
    }
#pragma unroll
    for (int rr = 0; rr < 8; ++rr) {
      const int rl = w * 16 + p * 8 + rr;      // local row 0..63
      const int r = r0 + rl;
      const float inv = 1.0f / den[rr];
      float a0 = num[rr][0] * inv, a1 = num[rr][1] * inv;
      float a2 = num[rr][2] * inv, a3 = num[rr][3] * inv;
      float s = a0 + a1 + a2 + a3;
      float sq = a0 * a0 + a1 * a1 + a2 * a2 + a3 * a3;
#pragma unroll
      for (int off = 1; off < 64; off <<= 1) { s += __shfl_xor(s, off); sq += __shfl_xor(sq, off); }
      const float mean = s * (1.0f / 256.0f);
      const float var = sq * (1.0f / 256.0f) - mean * mean;
      const float rstd = rsqrtf(var + 1e-5f);
      ushort4 hv = *(const ushort4*)&hqkv[(size_t)r * 1024 + l * 4];
      ushort4 o;
      o.x = f2bf(((a0 - mean) * rstd * g4.x + bb4.x) * (bf2f(hv.x) + be4.x));
      o.y = f2bf(((a1 - mean) * rstd * g4.y + bb4.y) * (bf2f(hv.y) + be4.y));
      o.z = f2bf(((a2 - mean) * rstd * g4.z + bb4.z) * (bf2f(hv.z) + be4.z));
      o.w = f2bf(((a3 - mean) * rstd * g4.w + bb4.w) * (bf2f(hv.w) + be4.w));
      // z col = 4l; phys slot = (l>>1) ^ (rl&15)
      *(ushort4*)&z_s[rl * 256 + (((l >> 1) ^ (rl & 15)) * 8) + (l & 1) * 4] = o;
    }
    // no barrier: q_s slice and z rows are wave-private
  }
  __syncthreads();                             // all z written; q_s/kv_s free

  // ---- phase 2: out = relu(z @ Wout + bout) + x0 ; B dbuf in kv_s region ----
  ushort* Bst = smem;                          // 2 x 8192 ushorts (32 KB)
  const int sr = t >> 2, sd = t & 3;
  const int ssl = sd ^ ((t >> 3) & 3);
  auto stageB = [&](int buf, int kt) {
#pragma unroll
    for (int i = 0; i < 4; ++i) {
      int row = i * 64 + sr;
      gload_lds16(&Woutt[(size_t)row * 256 + kt * 32 + ssl * 8],
                  &Bst[buf * 8192 + row * 32 + sd * 8]);
    }
  };
  stageB(0, 0);
  vm_drain();
  __syncthreads();
  const int fr = l & 15, fq = l >> 4;
  const int fsl = (fq ^ ((l >> 1) & 3)) * 8;
  f32x4 acc[4][4] = {};
#pragma unroll
  for (int kt = 0; kt < 8; ++kt) {
    const int cur = kt & 1;
    if (kt < 7) stageB(cur ^ 1, kt + 1);
    bf16x8 af[4], bfr[4];
#pragma unroll
    for (int f = 0; f < 4; ++f) {
      af[f]  = *(const bf16x8*)&z_s[(f * 16 + fr) * 256 + (((kt * 4 + fq) ^ fr) * 8)];
      bfr[f] = *(const bf16x8*)&Bst[cur * 8192 + (w * 64 + f * 16 + fr) * 32 + fsl];
    }
#pragma unroll
    for (int fm = 0; fm < 4; ++fm)
#pragma unroll
      for (int fn = 0; fn < 4; ++fn)
        acc[fm][fn] = __builtin_amdgcn_mfma_f32_16x16x32_bf16(af[fm], bfr[fn], acc[fm][fn], 0, 0, 0);
    vm_drain();
    __syncthreads();
  }
  float biasv[4];
#pragma unroll
  for (int fn = 0; fn < 4; ++fn) biasv[fn] = bout[w * 64 + fn * 16 + fr];
#pragma unroll
  for (int fm = 0; fm < 4; ++fm) {
#pragma unroll
    for (int fn = 0; fn < 4; ++fn) {
#pragma unroll
      for (int i = 0; i < 4; ++i) {
        const int row = fm * 16 + fq * 4 + i;  // 0..63
        const int col = w * 64 + fn * 16 + fr; // 0..255
        float v = fmaxf(acc[fm][fn][i] + biasv[fn], 0.0f);
        v += bf2f(x0b[(size_t)(r0 + row) * 256 + col]);
        out[(size_t)(r0 + row) * 256 + col] = v;
      }
    }
  }
}

// ---------------- host: launch -----------------------------------------------
extern "C" void kernel_launch(void* const* d_in, const int* in_sizes, int n_in,
                              void* d_out, int out_size, void* d_ws, size_t ws_size,
                              hipStream_t stream)
{
  const float* x    = (const float*)d_in[0];
  const float* np_  = (const float*)d_in[1];
  const float* Wh   = (const float*)d_in[2];
  const float* bh   = (const float*)d_in[3];
  const float* Wq   = (const float*)d_in[4];
  const float* bq   = (const float*)d_in[5];
  const float* Wk   = (const float*)d_in[6];
  const float* bk   = (const float*)d_in[7];
  const float* Wv   = (const float*)d_in[8];
  const float* bv   = (const float*)d_in[9];
  const float* Wout = (const float*)d_in[10];
  const float* bout = (const float*)d_in[11];
  const float* ln1g = (const float*)d_in[12];
  const float* ln1b = (const float*)d_in[13];
  const float* ln2g = (const float*)d_in[14];
  const float* ln2b = (const float*)d_in[15];
  const float* beta = (const float*)d_in[16];
  float* out = (float*)d_out;

  uintptr_t p = (uintptr_t)d_ws;
  ushort* x0b    = (ushort*)p; p += (size_t)65536 * 256 * 2;   // 33.5 MB
  ushort* hqkv   = (ushort*)p; p += (size_t)65536 * 1024 * 2;  // 134 MB
  ushort* zb     = (ushort*)p; p += (size_t)65536 * 256 * 2;   // (unused now)
  ushort* Wcat_t = (ushort*)p; p += (size_t)1024 * 256 * 2;
  ushort* Woutt  = (ushort*)p; p += (size_t)256 * 256 * 2;
  float*  bcat   = (float*)p;  p += (size_t)1024 * 4;
  float*  kv     = (float*)p;  p += (size_t)65536 * 4;
  float*  ksum   = (float*)p;  p += (size_t)2048 * 4;
  (void)zb;

  ln1_k<<<16384, 256, 0, stream>>>(x, ln1g, ln1b, x0b,
                                   Wh, Wq, Wk, Wv, Wout, bh, bq, bk, bv,
                                   Wcat_t, Woutt, bcat, kv, ksum);
  gemm_bf16_k<0><<<4096, 256, 0, stream>>>(x0b, Wcat_t, bcat, np_, nullptr, hqkv, nullptr);
  kvred_k<<<1024, 256, 0, stream>>>(hqkv, kv, ksum);
  attout_k<<<1024, 256, 0, stream>>>(hqkv, kv, ksum, ln2g, ln2b, beta,
                                     Woutt, bout, x0b, out);
}

// Round 15
// 202.392 us; speedup vs baseline: 1.4812x; 1.4812x over previous
//
#include <hip/hip_runtime.h>
#include <cstdint>

// WeightedPolynormerGlobal: B=8, NMAX=8192, D=256, H=8, DH=32, rows N=65536.
// Pipeline: prep+LN1 -> fused GEMM (h|q|k|v) -> kv/ksum reduce -> fused
//           attn+LN2+outGEMM (z never hits HBM).
// R5: gemm structure (BK=32, 4 blocks/CU, staged epilogue) -> gemm0 81us.
// R12: kvred per-wave chunks + 4x4 register blocking.
// R13: fused attnz+gemm1 (attout_k), z in swizzled LDS. Total 196.5us.
// R14: 8-row passes + ksum-in-regs -> VGPR spill (FETCH 209MB, WRITE 332MB),
//      attout 187us. REVERTED the register blowup.
// R15: R13 attout exactly, with ONLY the barrier-removal lever: wave-private
//      4-row q passes (per-wave gload_lds + vm_drain, zero block barriers in
//      phase 1). Register footprint = R13.

#define DEVI __device__ __forceinline__

typedef __attribute__((ext_vector_type(8))) short bf16x8;   // 8 bf16 in 4 VGPRs
typedef __attribute__((ext_vector_type(4))) float f32x4;

DEVI ushort f2bf(float f) {  // RNE float->bf16
  uint32_t u = __float_as_uint(f);
  u += 0x7FFFu + ((u >> 16) & 1u);
  return (ushort)(u >> 16);
}
DEVI float bf2f(ushort h) { return __uint_as_float(((uint32_t)h) << 16); }

DEVI void gload_lds16(const void* g, void* l) {
  __builtin_amdgcn_global_load_lds((const __attribute__((address_space(1))) void*)g,
                                   (__attribute__((address_space(3))) void*)l, 16, 0, 0);
}
DEVI void vm_drain() { asm volatile("s_waitcnt vmcnt(0)" ::: "memory"); }

// ---------------- K1: prep (weights->bf16 transposed, zero accum) + LN1 ------
__global__ __launch_bounds__(256)
void ln1_k(const float* __restrict__ x, const float* __restrict__ g1,
           const float* __restrict__ b1, ushort* __restrict__ x0b,
           const float* __restrict__ Wh, const float* __restrict__ Wq,
           const float* __restrict__ Wk, const float* __restrict__ Wv,
           const float* __restrict__ Wout,
           const float* __restrict__ bh, const float* __restrict__ bq,
           const float* __restrict__ bk, const float* __restrict__ bv,
           ushort* __restrict__ Wcat_t, ushort* __restrict__ Woutt,
           float* __restrict__ bcat, float* __restrict__ kv, float* __restrict__ ksum)
{
  const int t = threadIdx.x;
  const int idx = blockIdx.x * 256 + t;
  if (idx < 396288) {
    if (idx < 262144) {                       // Wcat_t[j][kk] = W_g[kk][jj]
      int j = idx >> 8, kk = idx & 255;
      int g = j >> 8, jj = j & 255;
      const float* W = (g == 0) ? Wh : (g == 1) ? Wq : (g == 2) ? Wk : Wv;
      Wcat_t[idx] = f2bf(W[kk * 256 + jj]);
    }
    int i2 = idx - 262144;
    if (i2 >= 0 && i2 < 65536) {              // Woutt[j][kk] = Wout[kk][j]
      int j = i2 >> 8, kk = i2 & 255;
      Woutt[i2] = f2bf(Wout[kk * 256 + j]);
    }
    int i3 = idx - (262144 + 65536);
    if (i3 >= 0 && i3 < 1024) {
      int g = i3 >> 8, jj = i3 & 255;
      const float* bb = (g == 0) ? bh : (g == 1) ? bq : (g == 2) ? bk : bv;
      bcat[i3] = bb[jj];
    }
    int i4 = idx - (262144 + 65536 + 1024);
    if (i4 >= 0 && i4 < 65536) kv[i4] = 0.0f;
    int i5 = idx - (262144 + 65536 + 1024 + 65536);
    if (i5 >= 0 && i5 < 2048) ksum[i5] = 0.0f;
  }
  const int l = t & 63, w = t >> 6;
  const size_t r = (size_t)blockIdx.x * 4 + w;
  const float4 xv = *(const float4*)&x[r * 256 + l * 4];
  float s = xv.x + xv.y + xv.z + xv.w;
  float sq = xv.x * xv.x + xv.y * xv.y + xv.z * xv.z + xv.w * xv.w;
#pragma unroll
  for (int off = 1; off < 64; off <<= 1) { s += __shfl_xor(s, off); sq += __shfl_xor(sq, off); }
  const float mean = s * (1.0f / 256.0f);
  const float var = sq * (1.0f / 256.0f) - mean * mean;
  const float rstd = rsqrtf(var + 1e-5f);
  const float4 g4 = *(const float4*)&g1[l * 4];
  const float4 b4 = *(const float4*)&b1[l * 4];
  ushort4 o;
  o.x = f2bf((xv.x - mean) * rstd * g4.x + b4.x);
  o.y = f2bf((xv.y - mean) * rstd * g4.y + b4.y);
  o.z = f2bf((xv.z - mean) * rstd * g4.z + b4.z);
  o.w = f2bf((xv.w - mean) * rstd * g4.w + b4.w);
  *(ushort4*)&x0b[r * 256 + l * 4] = o;
}

// ---------------- K2: bf16 MFMA GEMM (h|q|k|v), 128x128 tile, BK=32 ----------
template <int MODE>
__global__ __launch_bounds__(256, 4)
void gemm_bf16_k(const ushort* __restrict__ A, const ushort* __restrict__ Bt,
                 const float* __restrict__ bias, const float* __restrict__ node_prob,
                 const ushort* __restrict__ x0b, ushort* __restrict__ outb,
                 float* __restrict__ outf)
{
  __shared__ ushort smem[16384];               // 32 KB
  const int t = threadIdx.x;
  const int l = t & 63;
  const int w = t >> 6;
  const int wr = w >> 1, wc = w & 1;           // 2x2 waves of 64x64
  const int nNB = (MODE == 0) ? 8 : 2;
  const int per = gridDim.x >> 3;
  const int tile = (blockIdx.x & 7) * per + (blockIdx.x >> 3);
  const int m0 = (tile / nNB) * 128, n0 = (tile % nNB) * 128;
  const int sr = t >> 2;
  const int sd = t & 3;
  const int ssl = sd ^ ((t >> 3) & 3);         // pre-swizzled global src slot
  f32x4 acc[4][4] = {};

  auto stage = [&](int buf, int kt) {
#pragma unroll
    for (int i = 0; i < 2; ++i) {
      int row = i * 64 + sr;
      gload_lds16(&A[(size_t)(m0 + row) * 256 + kt * 32 + ssl * 8],
                  &smem[buf * 4096 + row * 32 + sd * 8]);
    }
#pragma unroll
    for (int i = 0; i < 2; ++i) {
      int row = i * 64 + sr;
      gload_lds16(&Bt[(size_t)(n0 + row) * 256 + kt * 32 + ssl * 8],
                  &smem[8192 + buf * 4096 + row * 32 + sd * 8]);
    }
  };

  stage(0, 0);
  vm_drain();
  __syncthreads();
  const int fr = l & 15;
  const int fq = l >> 4;
  const int fsl = (fq ^ ((l >> 1) & 3)) * 8;
#pragma unroll
  for (int kt = 0; kt < 8; ++kt) {
    const int cur = kt & 1;
    if (kt < 7) stage(cur ^ 1, kt + 1);
    bf16x8 af[4], bfr[4];
#pragma unroll
    for (int f = 0; f < 4; ++f) {
      af[f]  = *(const bf16x8*)&smem[cur * 4096 + (wr * 64 + f * 16 + fr) * 32 + fsl];
      bfr[f] = *(const bf16x8*)&smem[8192 + cur * 4096 + (wc * 64 + f * 16 + fr) * 32 + fsl];
    }
#pragma unroll
    for (int fm = 0; fm < 4; ++fm)
#pragma unroll
      for (int fn = 0; fn < 4; ++fn)
        acc[fm][fn] = __builtin_amdgcn_mfma_f32_16x16x32_bf16(af[fm], bfr[fn], acc[fm][fn], 0, 0, 0);
    vm_drain();
    __syncthreads();
  }

  float biasv[4];
#pragma unroll
  for (int fn = 0; fn < 4; ++fn) biasv[fn] = bias[n0 + wc * 64 + fn * 16 + fr];
  const int g = n0 >> 8;
#pragma unroll
  for (int fm = 0; fm < 4; ++fm) {
#pragma unroll
    for (int fn = 0; fn < 4; ++fn) {
#pragma unroll
      for (int i = 0; i < 4; ++i) {
        const int row = wr * 64 + fm * 16 + fq * 4 + i;
        const int col = wc * 64 + fn * 16 + fr;
        float v = acc[fm][fn][i] + biasv[fn];
        if (MODE == 0) {
          if (g == 1 || g == 2) v = 1.0f / (1.0f + __expf(-v));
          if (g == 2) v *= node_prob[m0 + row];
        } else {
          v = fmaxf(v, 0.0f);
        }
        smem[row * 128 + (col ^ ((row & 7) << 4))] = f2bf(v);
      }
    }
  }
  __syncthreads();
#pragma unroll
  for (int it = 0; it < 8; ++it) {
    const int row = w * 32 + it * 4 + fq;
    const int c8 = fr * 8;
    bf16x8 u = *(const bf16x8*)&smem[row * 128 + (c8 ^ ((row & 7) << 4))];
    if (MODE == 0) {
      *(bf16x8*)&outb[(size_t)(m0 + row) * 1024 + n0 + c8] = u;
    } else {
      bf16x8 xv = *(const bf16x8*)&x0b[(size_t)(m0 + row) * 256 + n0 + c8];
      float4 o0, o1;
      o0.x = bf2f((ushort)u[0]) + bf2f((ushort)xv[0]);
      o0.y = bf2f((ushort)u[1]) + bf2f((ushort)xv[1]);
      o0.z = bf2f((ushort)u[2]) + bf2f((ushort)xv[2]);
      o0.w = bf2f((ushort)u[3]) + bf2f((ushort)xv[3]);
      o1.x = bf2f((ushort)u[4]) + bf2f((ushort)xv[4]);
      o1.y = bf2f((ushort)u[5]) + bf2f((ushort)xv[5]);
      o1.z = bf2f((ushort)u[6]) + bf2f((ushort)xv[6]);
      o1.w = bf2f((ushort)u[7]) + bf2f((ushort)xv[7]);
      *(float4*)&outf[(size_t)(m0 + row) * 256 + n0 + c8] = o0;
      *(float4*)&outf[(size_t)(m0 + row) * 256 + n0 + c8 + 4] = o1;
    }
  }
}

// ---------------- K3: kv/ksum reduce (R12: per-wave chunks, 4x4 reg block) ---
__global__ __launch_bounds__(256)
void kvred_k(const ushort* __restrict__ hqkv, float* __restrict__ kv, float* __restrict__ ksum)
{
  __shared__ ushort smem[32768];               // 64KB: wave w: k @ w*8192, v @ +4096
  const int t = threadIdx.x, l = t & 63, w = t >> 6;
  const int bh = blockIdx.x >> 4, cb = blockIdx.x & 15;
  const int b = bh >> 3, h = bh & 7;
  const size_t nbase = (size_t)b * 8192 + cb * 512 + w * 128;
  ushort* kt = &smem[w * 8192];
  ushort* vt = &smem[w * 8192 + 4096];
#pragma unroll
  for (int i = 0; i < 8; ++i) {
    size_t row = nbase + i * 16 + (l >> 2);
    gload_lds16(&hqkv[row * 1024 + 512 + h * 32 + (l & 3) * 8], &kt[i * 512 + l * 8]);
  }
#pragma unroll
  for (int i = 0; i < 8; ++i) {
    size_t row = nbase + i * 16 + (l >> 2);
    gload_lds16(&hqkv[row * 1024 + 768 + h * 32 + (l & 3) * 8], &vt[i * 512 + l * 8]);
  }
  vm_drain();

  const int d0 = (l & 7) * 4, e0 = (l >> 3) * 4;
  float acc[4][4] = {};
  float ks0 = 0, ks1 = 0, ks2 = 0, ks3 = 0;
#pragma unroll 8
  for (int nn = 0; nn < 128; ++nn) {
    ushort4 kk = *(const ushort4*)&kt[nn * 32 + d0];
    ushort4 vv = *(const ushort4*)&vt[nn * 32 + e0];
    float k0 = bf2f(kk.x), k1 = bf2f(kk.y), k2 = bf2f(kk.z), k3 = bf2f(kk.w);
    float v0 = bf2f(vv.x), v1 = bf2f(vv.y), v2 = bf2f(vv.z), v3 = bf2f(vv.w);
    acc[0][0] += k0 * v0; acc[0][1] += k0 * v1; acc[0][2] += k0 * v2; acc[0][3] += k0 * v3;
    acc[1][0] += k1 * v0; acc[1][1] += k1 * v1; acc[1][2] += k1 * v2; acc[1][3] += k1 * v3;
    acc[2][0] += k2 * v0; acc[2][1] += k2 * v1; acc[2][2] += k2 * v2; acc[2][3] += k2 * v3;
    acc[3][0] += k3 * v0; acc[3][1] += k3 * v1; acc[3][2] += k3 * v2; acc[3][3] += k3 * v3;
    ks0 += k0; ks1 += k1; ks2 += k2; ks3 += k3;
  }
  __syncthreads();
  float* part = (float*)(void*)smem;
#pragma unroll
  for (int dd = 0; dd < 4; ++dd)
#pragma unroll
    for (int ee = 0; ee < 4; ++ee)
      part[w * 1024 + (dd * 4 + ee) * 64 + l] = acc[dd][ee];
  if (l < 8) {
    part[4096 + w * 32 + l * 4 + 0] = ks0;
    part[4096 + w * 32 + l * 4 + 1] = ks1;
    part[4096 + w * 32 + l * 4 + 2] = ks2;
    part[4096 + w * 32 + l * 4 + 3] = ks3;
  }
  __syncthreads();
  const int lsrc = t & 63;
#pragma unroll
  for (int j = 0; j < 4; ++j) {
    const int val = (t >> 6) * 4 + j;
    float s = part[0 * 1024 + val * 64 + lsrc] + part[1 * 1024 + val * 64 + lsrc]
            + part[2 * 1024 + val * 64 + lsrc] + part[3 * 1024 + val * 64 + lsrc];
    const int d = (lsrc & 7) * 4 + (val >> 2);
    const int e = (lsrc >> 3) * 4 + (val & 3);
    atomicAdd(&kv[(size_t)bh * 1024 + d * 32 + e], s);
  }
  if (t < 32) {
    float s = part[4096 + t] + part[4096 + 32 + t] + part[4096 + 64 + t] + part[4096 + 96 + t];
    atomicAdd(&ksum[bh * 32 + t], s);
  }
}

// ---------------- K4: FUSED attn+LN2+outGEMM ---------------------------------
// 64 rows/block, 1024 blocks. LDS 73KB (2 blocks/CU), layout = R13:
//   [0,32KB): kv_s f32 (phase1) / Woutt dbuf Bst (phase2)
//   [32KB,33KB): ks_s; [33KB,41KB): q_s (wave-private 4-row slices, 2KB/wave)
//   [41KB,73KB): z_s bf16 64x256, slot-swizzled phys = slot ^ (row&15)
// Phase1 (barrier-free): wave w owns rows w*16..+15 in four 4-row passes;
//   q staged per-wave (gload_lds + per-wave drain); num[4][4] (R13 regs).
// Phase2: gemm1 K-loop, A from z tile, relu+bout+x0 residual, f32 stores.
__global__ __launch_bounds__(256, 2)
void attout_k(const ushort* __restrict__ hqkv, const float* __restrict__ kv,
              const float* __restrict__ ksum, const float* __restrict__ g2,
              const float* __restrict__ b2, const float* __restrict__ beta,
              const ushort* __restrict__ Woutt, const float* __restrict__ bout,
              const ushort* __restrict__ x0b, float* __restrict__ out)
{
  __shared__ ushort smem[37376];               // 74752 B
  float* kv_s = (float*)(void*)smem;           // 8192 f32
  float* ks_s = (float*)(void*)(smem + 16384); // 256 f32
  ushort* q_s = smem + 16896;                  // [w][4][256] per pass (2KB/wave)
  ushort* z_s = smem + 20992;                  // 64x256 bf16 (swizzled)

  const int t = threadIdx.x, l = t & 63, w = t >> 6;
  const int r0 = blockIdx.x * 64;
  const int b = r0 >> 13;

#pragma unroll
  for (int i = 0; i < 8; ++i)
    *(float4*)&kv_s[i * 1024 + t * 4] = *(const float4*)&kv[(size_t)b * 8192 + i * 1024 + t * 4];
  if (t < 64) *(float4*)&ks_s[t * 4] = *(const float4*)&ksum[b * 256 + t * 4];
  __syncthreads();                             // kv_s/ks_s published (read-only after)

  const int h = l >> 3, e0 = (l & 7) * 4;
  const float4 g4 = *(const float4*)&g2[l * 4];
  const float4 bb4 = *(const float4*)&b2[l * 4];
  const float4 be4 = *(const float4*)&beta[l * 4];

  for (int p = 0; p < 4; ++p) {                // four 4-row passes, wave-private
#pragma unroll
    for (int j = 0; j < 2; ++j) {              // stage wave's 4 q rows (2 rows/instr)
      int row = p * 4 + j * 2 + (l >> 5);      // row within wave's 16
      gload_lds16(&hqkv[(size_t)(r0 + w * 16 + row) * 1024 + 256 + (l & 31) * 8],
                  &q_s[w * 1024 + j * 512 + l * 8]);
    }
    vm_drain();                                // private slice ready (this wave only)
    float num[4][4] = {};
    float den[4] = {0.0f, 0.0f, 0.0f, 0.0f};
#pragma unroll
    for (int dl = 0; dl < 8; ++dl) {
      const float4 ks4 = *(const float4*)&ks_s[h * 32 + dl * 4];
      float4 kvv[4];
#pragma unroll
      for (int cc = 0; cc < 4; ++cc)
        kvv[cc] = *(const float4*)&kv_s[h * 1024 + (dl * 4 + cc) * 32 + e0];
#pragma unroll
      for (int rr = 0; rr < 4; ++rr) {
        ushort4 qv = *(const ushort4*)&q_s[w * 1024 + rr * 256 + h * 32 + dl * 4];
        float qx = bf2f(qv.x), qy = bf2f(qv.y), qz = bf2f(qv.z), qw = bf2f(qv.w);
        den[rr] += qx * ks4.x + qy * ks4.y + qz * ks4.z + qw * ks4.w;
        num[rr][0] += qx * kvv[0].x + qy * kvv[1].x + qz * kvv[2].x + qw * kvv[3].x;
        num[rr][1] += qx * kvv[0].y + qy * kvv[1].y + qz * kvv[2].y + qw * kvv[3].y;
        num[rr][2] += qx * kvv[0].z + qy * kvv[1].z + qz * kvv[2].z + qw * kvv[3].z;
        num[rr][3] += qx * kvv[0].w + qy * kvv[1].w + qz * kvv[2].w + qw * kvv[3].w;
      }
    }
#pragma unroll
    for (int rr = 0; rr < 4; ++rr) {
      const int rl = w * 16 + p * 4 + rr;      // local row 0..63
      const int r = r0 + rl;
      const float inv = 1.0f / den[rr];
      float a0 = num[rr][0] * inv, a1 = num[rr][1] * inv;
      float a2 = num[rr][2] * inv, a3 = num[rr][3] * inv;
      float s = a0 + a1 + a2 + a3;
      float sq = a0 * a0 + a1 * a1 + a2 * a2 + a3 * a3;
#pragma unroll
      for (int off = 1; off < 64; off <<= 1) { s += __shfl_xor(s, off); sq += __shfl_xor(sq, off); }
      const float mean = s * (1.0f / 256.0f);
      const float var = sq * (1.0f / 256.0f) - mean * mean;
      const float rstd = rsqrtf(var + 1e-5f);
      ushort4 hv = *(const ushort4*)&hqkv[(size_t)r * 1024 + l * 4];
      ushort4 o;
      o.x = f2bf(((a0 - mean) * rstd * g4.x + bb4.x) * (bf2f(hv.x) + be4.x));
      o.y = f2bf(((a1 - mean) * rstd * g4.y + bb4.y) * (bf2f(hv.y) + be4.y));
      o.z = f2bf(((a2 - mean) * rstd * g4.z + bb4.z) * (bf2f(hv.z) + be4.z));
      o.w = f2bf(((a3 - mean) * rstd * g4.w + bb4.w) * (bf2f(hv.w) + be4.w));
      // z col = 4l; phys slot = (l>>1) ^ (rl&15)
      *(ushort4*)&z_s[rl * 256 + (((l >> 1) ^ (rl & 15)) * 8) + (l & 1) * 4] = o;
    }
    // no barrier: q_s slice and z rows are wave-private
  }
  __syncthreads();                             // all z written; q_s/kv_s free

  // ---- phase 2: out = relu(z @ Wout + bout) + x0 ; B dbuf in kv_s region ----
  ushort* Bst = smem;                          // 2 x 8192 ushorts (32 KB)
  const int sr = t >> 2, sd = t & 3;
  const int ssl = sd ^ ((t >> 3) & 3);
  auto stageB = [&](int buf, int kt) {
#pragma unroll
    for (int i = 0; i < 4; ++i) {
      int row = i * 64 + sr;
      gload_lds16(&Woutt[(size_t)row * 256 + kt * 32 + ssl * 8],
                  &Bst[buf * 8192 + row * 32 + sd * 8]);
    }
  };
  stageB(0, 0);
  vm_drain();
  __syncthreads();
  const int fr = l & 15, fq = l >> 4;
  const int fsl = (fq ^ ((l >> 1) & 3)) * 8;
  f32x4 acc[4][4] = {};
#pragma unroll
  for (int kt = 0; kt < 8; ++kt) {
    const int cur = kt & 1;
    if (kt < 7) stageB(cur ^ 1, kt + 1);
    bf16x8 af[4], bfr[4];
#pragma unroll
    for (int f = 0; f < 4; ++f) {
      af[f]  = *(const bf16x8*)&z_s[(f * 16 + fr) * 256 + (((kt * 4 + fq) ^ fr) * 8)];
      bfr[f] = *(const bf16x8*)&Bst[cur * 8192 + (w * 64 + f * 16 + fr) * 32 + fsl];
    }
#pragma unroll
    for (int fm = 0; fm < 4; ++fm)
#pragma unroll
      for (int fn = 0; fn < 4; ++fn)
        acc[fm][fn] = __builtin_amdgcn_mfma_f32_16x16x32_bf16(af[fm], bfr[fn], acc[fm][fn], 0, 0, 0);
    vm_drain();
    __syncthreads();
  }
  float biasv[4];
#pragma unroll
  for (int fn = 0; fn < 4; ++fn) biasv[fn] = bout[w * 64 + fn * 16 + fr];
#pragma unroll
  for (int fm = 0; fm < 4; ++fm) {
#pragma unroll
    for (int fn = 0; fn < 4; ++fn) {
#pragma unroll
      for (int i = 0; i < 4; ++i) {
        const int row = fm * 16 + fq * 4 + i;  // 0..63
        const int col = w * 64 + fn * 16 + fr; // 0..255
        float v = fmaxf(acc[fm][fn][i] + biasv[fn], 0.0f);
        v += bf2f(x0b[(size_t)(r0 + row) * 256 + col]);
        out[(size_t)(r0 + row) * 256 + col] = v;
      }
    }
  }
}

// ---------------- host: launch -----------------------------------------------
extern "C" void kernel_launch(void* const* d_in, const int* in_sizes, int n_in,
                              void* d_out, int out_size, void* d_ws, size_t ws_size,
                              hipStream_t stream)
{
  const float* x    = (const float*)d_in[0];
  const float* np_  = (const float*)d_in[1];
  const float* Wh   = (const float*)d_in[2];
  const float* bh   = (const float*)d_in[3];
  const float* Wq   = (const float*)d_in[4];
  const float* bq   = (const float*)d_in[5];
  const float* Wk   = (const float*)d_in[6];
  const float* bk   = (const float*)d_in[7];
  const float* Wv   = (const float*)d_in[8];
  const float* bv   = (const float*)d_in[9];
  const float* Wout = (const float*)d_in[10];
  const float* bout = (const float*)d_in[11];
  const float* ln1g = (const float*)d_in[12];
  const float* ln1b = (const float*)d_in[13];
  const float* ln2g = (const float*)d_in[14];
  const float* ln2b = (const float*)d_in[15];
  const float* beta = (const float*)d_in[16];
  float* out = (float*)d_out;

  uintptr_t p = (uintptr_t)d_ws;
  ushort* x0b    = (ushort*)p; p += (size_t)65536 * 256 * 2;   // 33.5 MB
  ushort* hqkv   = (ushort*)p; p += (size_t)65536 * 1024 * 2;  // 134 MB
  ushort* zb     = (ushort*)p; p += (size_t)65536 * 256 * 2;   // (unused now)
  ushort* Wcat_t = (ushort*)p; p += (size_t)1024 * 256 * 2;
  ushort* Woutt  = (ushort*)p; p += (size_t)256 * 256 * 2;
  float*  bcat   = (float*)p;  p += (size_t)1024 * 4;
  float*  kv     = (float*)p;  p += (size_t)65536 * 4;
  float*  ksum   = (float*)p;  p += (size_t)2048 * 4;
  (void)zb;

  ln1_k<<<16384, 256, 0, stream>>>(x, ln1g, ln1b, x0b,
                                   Wh, Wq, Wk, Wv, Wout, bh, bq, bk, bv,
                                   Wcat_t, Woutt, bcat, kv, ksum);
  gemm_bf16_k<0><<<4096, 256, 0, stream>>>(x0b, Wcat_t, bcat, np_, nullptr, hqkv, nullptr);
  kvred_k<<<1024, 256, 0, stream>>>(hqkv, kv, ksum);
  attout_k<<<1024, 256, 0, stream>>>(hqkv, kv, ksum, ln2g, ln2b, beta,
                                     Woutt, bout, x0b, out);
}

// Round 16
// 172.542 us; speedup vs baseline: 1.7375x; 1.1730x over previous
//
#include <hip/hip_runtime.h>
#include <cstdint>

// WeightedPolynormerGlobal: B=8, NMAX=8192, D=256, H=8, DH=32, rows N=65536.
// Pipeline: prep+LN1 -> fused GEMM (h|q|k|v) -> kv/ksum reduce -> fused
//           attn+LN2+outGEMM (attout_k; z never hits HBM).
// R5: gemm structure (BK=32, 4 blocks/CU, staged epilogue) -> gemm0 81us.
// R13: fused attnz+gemm1. R15: barrier removal null -> phase1 is VALU-work
//      bound (num=q*kv as scalar FMA), not barrier bound.
// R16: MFMA-ize phase 1 — kvT bf16 in LDS as B operand, q A-frags direct from
//      global, one 16x16x32 MFMA per tile (K=32 in one op); den via VALU dot;
//      cross-wave LN2 via LDS partials. 32 rows/block, LDS 48KB -> 3 blocks/CU.

#define DEVI __device__ __forceinline__

typedef __attribute__((ext_vector_type(8))) short bf16x8;   // 8 bf16 in 4 VGPRs
typedef __attribute__((ext_vector_type(4))) float f32x4;

DEVI ushort f2bf(float f) {  // RNE float->bf16
  uint32_t u = __float_as_uint(f);
  u += 0x7FFFu + ((u >> 16) & 1u);
  return (ushort)(u >> 16);
}
DEVI float bf2f(ushort h) { return __uint_as_float(((uint32_t)h) << 16); }

DEVI void gload_lds16(const void* g, void* l) {
  __builtin_amdgcn_global_load_lds((const __attribute__((address_space(1))) void*)g,
                                   (__attribute__((address_space(3))) void*)l, 16, 0, 0);
}
DEVI void vm_drain() { asm volatile("s_waitcnt vmcnt(0)" ::: "memory"); }

// ---------------- K1: prep (weights->bf16 transposed, zero accum) + LN1 ------
__global__ __launch_bounds__(256)
void ln1_k(const float* __restrict__ x, const float* __restrict__ g1,
           const float* __restrict__ b1, ushort* __restrict__ x0b,
           const float* __restrict__ Wh, const float* __restrict__ Wq,
           const float* __restrict__ Wk, const float* __restrict__ Wv,
           const float* __restrict__ Wout,
           const float* __restrict__ bh, const float* __restrict__ bq,
           const float* __restrict__ bk, const float* __restrict__ bv,
           ushort* __restrict__ Wcat_t, ushort* __restrict__ Woutt,
           float* __restrict__ bcat, float* __restrict__ kv, float* __restrict__ ksum)
{
  const int t = threadIdx.x;
  const int idx = blockIdx.x * 256 + t;
  if (idx < 396288) {
    if (idx < 262144) {                       // Wcat_t[j][kk] = W_g[kk][jj]
      int j = idx >> 8, kk = idx & 255;
      int g = j >> 8, jj = j & 255;
      const float* W = (g == 0) ? Wh : (g == 1) ? Wq : (g == 2) ? Wk : Wv;
      Wcat_t[idx] = f2bf(W[kk * 256 + jj]);
    }
    int i2 = idx - 262144;
    if (i2 >= 0 && i2 < 65536) {              // Woutt[j][kk] = Wout[kk][j]
      int j = i2 >> 8, kk = i2 & 255;
      Woutt[i2] = f2bf(Wout[kk * 256 + j]);
    }
    int i3 = idx - (262144 + 65536);
    if (i3 >= 0 && i3 < 1024) {
      int g = i3 >> 8, jj = i3 & 255;
      const float* bb = (g == 0) ? bh : (g == 1) ? bq : (g == 2) ? bk : bv;
      bcat[i3] = bb[jj];
    }
    int i4 = idx - (262144 + 65536 + 1024);
    if (i4 >= 0 && i4 < 65536) kv[i4] = 0.0f;
    int i5 = idx - (262144 + 65536 + 1024 + 65536);
    if (i5 >= 0 && i5 < 2048) ksum[i5] = 0.0f;
  }
  const int l = t & 63, w = t >> 6;
  const size_t r = (size_t)blockIdx.x * 4 + w;
  const float4 xv = *(const float4*)&x[r * 256 + l * 4];
  float s = xv.x + xv.y + xv.z + xv.w;
  float sq = xv.x * xv.x + xv.y * xv.y + xv.z * xv.z + xv.w * xv.w;
#pragma unroll
  for (int off = 1; off < 64; off <<= 1) { s += __shfl_xor(s, off); sq += __shfl_xor(sq, off); }
  const float mean = s * (1.0f / 256.0f);
  const float var = sq * (1.0f / 256.0f) - mean * mean;
  const float rstd = rsqrtf(var + 1e-5f);
  const float4 g4 = *(const float4*)&g1[l * 4];
  const float4 b4 = *(const float4*)&b1[l * 4];
  ushort4 o;
  o.x = f2bf((xv.x - mean) * rstd * g4.x + b4.x);
  o.y = f2bf((xv.y - mean) * rstd * g4.y + b4.y);
  o.z = f2bf((xv.z - mean) * rstd * g4.z + b4.z);
  o.w = f2bf((xv.w - mean) * rstd * g4.w + b4.w);
  *(ushort4*)&x0b[r * 256 + l * 4] = o;
}

// ---------------- K2: bf16 MFMA GEMM (h|q|k|v), 128x128 tile, BK=32 ----------
template <int MODE>
__global__ __launch_bounds__(256, 4)
void gemm_bf16_k(const ushort* __restrict__ A, const ushort* __restrict__ Bt,
                 const float* __restrict__ bias, const float* __restrict__ node_prob,
                 const ushort* __restrict__ x0b, ushort* __restrict__ outb,
                 float* __restrict__ outf)
{
  __shared__ ushort smem[16384];               // 32 KB
  const int t = threadIdx.x;
  const int l = t & 63;
  const int w = t >> 6;
  const int wr = w >> 1, wc = w & 1;           // 2x2 waves of 64x64
  const int nNB = (MODE == 0) ? 8 : 2;
  const int per = gridDim.x >> 3;
  const int tile = (blockIdx.x & 7) * per + (blockIdx.x >> 3);
  const int m0 = (tile / nNB) * 128, n0 = (tile % nNB) * 128;
  const int sr = t >> 2;
  const int sd = t & 3;
  const int ssl = sd ^ ((t >> 3) & 3);         // pre-swizzled global src slot
  f32x4 acc[4][4] = {};

  auto stage = [&](int buf, int kt) {
#pragma unroll
    for (int i = 0; i < 2; ++i) {
      int row = i * 64 + sr;
      gload_lds16(&A[(size_t)(m0 + row) * 256 + kt * 32 + ssl * 8],
                  &smem[buf * 4096 + row * 32 + sd * 8]);
    }
#pragma unroll
    for (int i = 0; i < 2; ++i) {
      int row = i * 64 + sr;
      gload_lds16(&Bt[(size_t)(n0 + row) * 256 + kt * 32 + ssl * 8],
                  &smem[8192 + buf * 4096 + row * 32 + sd * 8]);
    }
  };

  stage(0, 0);
  vm_drain();
  __syncthreads();
  const int fr = l & 15;
  const int fq = l >> 4;
  const int fsl = (fq ^ ((l >> 1) & 3)) * 8;
#pragma unroll
  for (int kt = 0; kt < 8; ++kt) {
    const int cur = kt & 1;
    if (kt < 7) stage(cur ^ 1, kt + 1);
    bf16x8 af[4], bfr[4];
#pragma unroll
    for (int f = 0; f < 4; ++f) {
      af[f]  = *(const bf16x8*)&smem[cur * 4096 + (wr * 64 + f * 16 + fr) * 32 + fsl];
      bfr[f] = *(const bf16x8*)&smem[8192 + cur * 4096 + (wc * 64 + f * 16 + fr) * 32 + fsl];
    }
#pragma unroll
    for (int fm = 0; fm < 4; ++fm)
#pragma unroll
      for (int fn = 0; fn < 4; ++fn)
        acc[fm][fn] = __builtin_amdgcn_mfma_f32_16x16x32_bf16(af[fm], bfr[fn], acc[fm][fn], 0, 0, 0);
    vm_drain();
    __syncthreads();
  }

  float biasv[4];
#pragma unroll
  for (int fn = 0; fn < 4; ++fn) biasv[fn] = bias[n0 + wc * 64 + fn * 16 + fr];
  const int g = n0 >> 8;
#pragma unroll
  for (int fm = 0; fm < 4; ++fm) {
#pragma unroll
    for (int fn = 0; fn < 4; ++fn) {
#pragma unroll
      for (int i = 0; i < 4; ++i) {
        const int row = wr * 64 + fm * 16 + fq * 4 + i;
        const int col = wc * 64 + fn * 16 + fr;
        float v = acc[fm][fn][i] + biasv[fn];
        if (MODE == 0) {
          if (g == 1 || g == 2) v = 1.0f / (1.0f + __expf(-v));
          if (g == 2) v *= node_prob[m0 + row];
        } else {
          v = fmaxf(v, 0.0f);
        }
        smem[row * 128 + (col ^ ((row & 7) << 4))] = f2bf(v);
      }
    }
  }
  __syncthreads();
#pragma unroll
  for (int it = 0; it < 8; ++it) {
    const int row = w * 32 + it * 4 + fq;
    const int c8 = fr * 8;
    bf16x8 u = *(const bf16x8*)&smem[row * 128 + (c8 ^ ((row & 7) << 4))];
    if (MODE == 0) {
      *(bf16x8*)&outb[(size_t)(m0 + row) * 1024 + n0 + c8] = u;
    } else {
      bf16x8 xv = *(const bf16x8*)&x0b[(size_t)(m0 + row) * 256 + n0 + c8];
      float4 o0, o1;
      o0.x = bf2f((ushort)u[0]) + bf2f((ushort)xv[0]);
      o0.y = bf2f((ushort)u[1]) + bf2f((ushort)xv[1]);
      o0.z = bf2f((ushort)u[2]) + bf2f((ushort)xv[2]);
      o0.w = bf2f((ushort)u[3]) + bf2f((ushort)xv[3]);
      o1.x = bf2f((ushort)u[4]) + bf2f((ushort)xv[4]);
      o1.y = bf2f((ushort)u[5]) + bf2f((ushort)xv[5]);
      o1.z = bf2f((ushort)u[6]) + bf2f((ushort)xv[6]);
      o1.w = bf2f((ushort)u[7]) + bf2f((ushort)xv[7]);
      *(float4*)&outf[(size_t)(m0 + row) * 256 + n0 + c8] = o0;
      *(float4*)&outf[(size_t)(m0 + row) * 256 + n0 + c8 + 4] = o1;
    }
  }
}

// ---------------- K3: kv/ksum reduce (R12: per-wave chunks, 4x4 reg block) ---
__global__ __launch_bounds__(256)
void kvred_k(const ushort* __restrict__ hqkv, float* __restrict__ kv, float* __restrict__ ksum)
{
  __shared__ ushort smem[32768];               // 64KB: wave w: k @ w*8192, v @ +4096
  const int t = threadIdx.x, l = t & 63, w = t >> 6;
  const int bh = blockIdx.x >> 4, cb = blockIdx.x & 15;
  const int b = bh >> 3, h = bh & 7;
  const size_t nbase = (size_t)b * 8192 + cb * 512 + w * 128;
  ushort* kt = &smem[w * 8192];
  ushort* vt = &smem[w * 8192 + 4096];
#pragma unroll
  for (int i = 0; i < 8; ++i) {
    size_t row = nbase + i * 16 + (l >> 2);
    gload_lds16(&hqkv[row * 1024 + 512 + h * 32 + (l & 3) * 8], &kt[i * 512 + l * 8]);
  }
#pragma unroll
  for (int i = 0; i < 8; ++i) {
    size_t row = nbase + i * 16 + (l >> 2);
    gload_lds16(&hqkv[row * 1024 + 768 + h * 32 + (l & 3) * 8], &vt[i * 512 + l * 8]);
  }
  vm_drain();

  const int d0 = (l & 7) * 4, e0 = (l >> 3) * 4;
  float acc[4][4] = {};
  float ks0 = 0, ks1 = 0, ks2 = 0, ks3 = 0;
#pragma unroll 8
  for (int nn = 0; nn < 128; ++nn) {
    ushort4 kk = *(const ushort4*)&kt[nn * 32 + d0];
    ushort4 vv = *(const ushort4*)&vt[nn * 32 + e0];
    float k0 = bf2f(kk.x), k1 = bf2f(kk.y), k2 = bf2f(kk.z), k3 = bf2f(kk.w);
    float v0 = bf2f(vv.x), v1 = bf2f(vv.y), v2 = bf2f(vv.z), v3 = bf2f(vv.w);
    acc[0][0] += k0 * v0; acc[0][1] += k0 * v1; acc[0][2] += k0 * v2; acc[0][3] += k0 * v3;
    acc[1][0] += k1 * v0; acc[1][1] += k1 * v1; acc[1][2] += k1 * v2; acc[1][3] += k1 * v3;
    acc[2][0] += k2 * v0; acc[2][1] += k2 * v1; acc[2][2] += k2 * v2; acc[2][3] += k2 * v3;
    acc[3][0] += k3 * v0; acc[3][1] += k3 * v1; acc[3][2] += k3 * v2; acc[3][3] += k3 * v3;
    ks0 += k0; ks1 += k1; ks2 += k2; ks3 += k3;
  }
  __syncthreads();
  float* part = (float*)(void*)smem;
#pragma unroll
  for (int dd = 0; dd < 4; ++dd)
#pragma unroll
    for (int ee = 0; ee < 4; ++ee)
      part[w * 1024 + (dd * 4 + ee) * 64 + l] = acc[dd][ee];
  if (l < 8) {
    part[4096 + w * 32 + l * 4 + 0] = ks0;
    part[4096 + w * 32 + l * 4 + 1] = ks1;
    part[4096 + w * 32 + l * 4 + 2] = ks2;
    part[4096 + w * 32 + l * 4 + 3] = ks3;
  }
  __syncthreads();
  const int lsrc = t & 63;
#pragma unroll
  for (int j = 0; j < 4; ++j) {
    const int val = (t >> 6) * 4 + j;
    float s = part[0 * 1024 + val * 64 + lsrc] + part[1 * 1024 + val * 64 + lsrc]
            + part[2 * 1024 + val * 64 + lsrc] + part[3 * 1024 + val * 64 + lsrc];
    const int d = (lsrc & 7) * 4 + (val >> 2);
    const int e = (lsrc >> 3) * 4 + (val & 3);
    atomicAdd(&kv[(size_t)bh * 1024 + d * 32 + e], s);
  }
  if (t < 32) {
    float s = part[4096 + t] + part[4096 + 32 + t] + part[4096 + 64 + t] + part[4096 + 96 + t];
    atomicAdd(&ksum[bh * 32 + t], s);
  }
}

// ---------------- K4: FUSED attn(MFMA)+LN2+outGEMM ---------------------------
// 32 rows/block, 2048 blocks. LDS 48KB (3 blocks/CU):
//   region A [0,32KB): phase1 {kvT bf16 [h][e][d] swz @0 (16KB); ksum_s f32 @8192;
//     g2_s @8704; b2_s @9216; be_s @9728; part_s @10240; part_q @10496;
//     mean_s @10752; rstd_s @10816 (ushort offsets)} / phase2 Woutt dbuf (32KB)
//   z_s [32KB,48KB): 32x256 bf16, slot-swizzled phys = slot ^ (row&15)
// Phase1: wave w owns heads {2w,2w+1}; num via one 16x16x32 MFMA per
//   (mg,h,tile) with A=q frags from global, B=kvT; den via VALU dot + shfl;
//   LN2 via quarter xor-reduce + cross-wave LDS partials.
__global__ __launch_bounds__(256, 3)
void attout_k(const ushort* __restrict__ hqkv, const float* __restrict__ kv,
              const float* __restrict__ ksum, const float* __restrict__ g2,
              const float* __restrict__ b2, const float* __restrict__ beta,
              const ushort* __restrict__ Woutt, const float* __restrict__ bout,
              const ushort* __restrict__ x0b, float* __restrict__ out)
{
  __shared__ ushort smem[24576];               // 48 KB
  ushort* kvT   = smem;                        // [h][e][d] bf16, slot-swizzled
  float* ksum_s = (float*)(void*)(smem + 8192);
  float* g2_s   = (float*)(void*)(smem + 8704);
  float* b2_s   = (float*)(void*)(smem + 9216);
  float* be_s   = (float*)(void*)(smem + 9728);
  float* part_s = (float*)(void*)(smem + 10240);  // [4 waves][32 rows]
  float* part_q = (float*)(void*)(smem + 10496);
  float* mean_s = (float*)(void*)(smem + 10752);
  float* rstd_s = (float*)(void*)(smem + 10816);
  ushort* z_s   = smem + 16384;                // 32x256 bf16 swizzled

  const int t = threadIdx.x, l = t & 63, w = t >> 6;
  const int fr = l & 15, fq = l >> 4;
  const int r0 = blockIdx.x * 32;
  const int b = r0 >> 13;

  // ---- stage kvT (f32 -> bf16, transposed d<->e, slot-swizzled) + scalars ----
  ksum_s[t] = ksum[b * 256 + t];
  g2_s[t] = g2[t]; b2_s[t] = b2[t]; be_s[t] = beta[t];
#pragma unroll
  for (int i = 0; i < 8; ++i) {                // h = i
    float4 kvv = *(const float4*)&kv[(size_t)b * 8192 + i * 1024 + t * 4];
    const int d = (t * 4) >> 5;
    const int e0 = (t * 4) & 31;
    float va[4] = {kvv.x, kvv.y, kvv.z, kvv.w};
#pragma unroll
    for (int j = 0; j < 4; ++j) {
      const int e = e0 + j;
      kvT[i * 1024 + e * 32 + (((d >> 3) ^ (e & 3)) * 8) + (d & 7)] = f2bf(va[j]);
    }
  }
  __syncthreads();

  // ---- phase 1: num via MFMA, den via VALU dot, LN2 cross-wave --------------
  f32x4 att[2][2][2];                          // [mg][hh][tile]
  float s_[2][4] = {}, q_[2][4] = {};
  const f32x4 zf = {0.0f, 0.0f, 0.0f, 0.0f};
#pragma unroll
  for (int mg = 0; mg < 2; ++mg) {
#pragma unroll
    for (int hh = 0; hh < 2; ++hh) {
      const int h = w * 2 + hh;
      const bf16x8 af = *(const bf16x8*)&hqkv[(size_t)(r0 + mg * 16 + fr) * 1024 + 256 + h * 32 + fq * 8];
      const bf16x8 b0 = *(const bf16x8*)&kvT[h * 1024 + fr * 32 + ((fq ^ (fr & 3)) * 8)];
      const bf16x8 b1 = *(const bf16x8*)&kvT[h * 1024 + (16 + fr) * 32 + ((fq ^ (fr & 3)) * 8)];
      f32x4 n0 = __builtin_amdgcn_mfma_f32_16x16x32_bf16(af, b0, zf, 0, 0, 0);
      f32x4 n1 = __builtin_amdgcn_mfma_f32_16x16x32_bf16(af, b1, zf, 0, 0, 0);
      // den partial: q (this lane's 8 elems) . ksum slice
      const float4 ka = *(const float4*)&ksum_s[h * 32 + fq * 8];
      const float4 kb = *(const float4*)&ksum_s[h * 32 + fq * 8 + 4];
      float p = bf2f((ushort)af[0]) * ka.x + bf2f((ushort)af[1]) * ka.y
              + bf2f((ushort)af[2]) * ka.z + bf2f((ushort)af[3]) * ka.w
              + bf2f((ushort)af[4]) * kb.x + bf2f((ushort)af[5]) * kb.y
              + bf2f((ushort)af[6]) * kb.z + bf2f((ushort)af[7]) * kb.w;
      p += __shfl_xor(p, 16);
      p += __shfl_xor(p, 32);                  // den[fr] in every lane
#pragma unroll
      for (int i = 0; i < 4; ++i) {
        const float dv = __shfl(p, fq * 4 + i);  // den for this lane's row
        const float inv = 1.0f / dv;
        const float a0 = n0[i] * inv;
        const float a1 = n1[i] * inv;
        att[mg][hh][0][i] = a0;
        att[mg][hh][1][i] = a1;
        s_[mg][i] += a0 + a1;
        q_[mg][i] += a0 * a0 + a1 * a1;
      }
    }
  }
  // quarter xor-reduce (sum over this wave's 64 cols) + cross-wave partials
#pragma unroll
  for (int mg = 0; mg < 2; ++mg) {
#pragma unroll
    for (int i = 0; i < 4; ++i) {
#pragma unroll
      for (int off = 1; off < 16; off <<= 1) {
        s_[mg][i] += __shfl_xor(s_[mg][i], off);
        q_[mg][i] += __shfl_xor(q_[mg][i], off);
      }
    }
    if (fr == 0) {
      float4 sv = {s_[mg][0], s_[mg][1], s_[mg][2], s_[mg][3]};
      float4 qv = {q_[mg][0], q_[mg][1], q_[mg][2], q_[mg][3]};
      *(float4*)&part_s[w * 32 + mg * 16 + fq * 4] = sv;
      *(float4*)&part_q[w * 32 + mg * 16 + fq * 4] = qv;
    }
  }
  __syncthreads();
  if (t < 32) {
    const float ss = part_s[t] + part_s[32 + t] + part_s[64 + t] + part_s[96 + t];
    const float qq = part_q[t] + part_q[32 + t] + part_q[64 + t] + part_q[96 + t];
    const float mean = ss * (1.0f / 256.0f);
    const float var = qq * (1.0f / 256.0f) - mean * mean;
    mean_s[t] = mean;
    rstd_s[t] = rsqrtf(var + 1e-5f);
  }
  __syncthreads();

  // ---- z = LN2(att)*(h+beta) -> swizzled z_s --------------------------------
#pragma unroll
  for (int mg = 0; mg < 2; ++mg) {
    float mn[4], rs[4];
#pragma unroll
    for (int i = 0; i < 4; ++i) {
      const int row = mg * 16 + fq * 4 + i;
      mn[i] = mean_s[row];
      rs[i] = rstd_s[row];
    }
#pragma unroll
    for (int hh = 0; hh < 2; ++hh) {
#pragma unroll
      for (int tl = 0; tl < 2; ++tl) {
        const int j = (w * 2 + hh) * 32 + tl * 16 + fr;
        const float gg = g2_s[j], bb = b2_s[j], be = be_s[j];
#pragma unroll
        for (int i = 0; i < 4; ++i) {
          const int row = mg * 16 + fq * 4 + i;
          const float hvv = bf2f(hqkv[(size_t)(r0 + row) * 1024 + j]);
          const float zz = ((att[mg][hh][tl][i] - mn[i]) * rs[i] * gg + bb) * (hvv + be);
          z_s[row * 256 + (((j >> 3) ^ (row & 15)) * 8) + (j & 7)] = f2bf(zz);
        }
      }
    }
  }
  __syncthreads();                             // z complete; region A free

  // ---- phase 2: out = relu(z @ Wout + bout) + x0 ----------------------------
  ushort* Bst = smem;                          // 2 x 8192 ushorts (32 KB)
  const int sr = t >> 2, sd = t & 3;
  const int ssl = sd ^ ((t >> 3) & 3);
  auto stageB = [&](int buf, int kt) {
#pragma unroll
    for (int i = 0; i < 4; ++i) {
      int row = i * 64 + sr;
      gload_lds16(&Woutt[(size_t)row * 256 + kt * 32 + ssl * 8],
                  &Bst[buf * 8192 + row * 32 + sd * 8]);
    }
  };
  stageB(0, 0);
  vm_drain();
  __syncthreads();
  const int fsl = (fq ^ ((l >> 1) & 3)) * 8;
  f32x4 acc[2][4] = {};
#pragma unroll
  for (int kt = 0; kt < 8; ++kt) {
    const int cur = kt & 1;
    if (kt < 7) stageB(cur ^ 1, kt + 1);
    bf16x8 af2[2], bfr[4];
#pragma unroll
    for (int f = 0; f < 2; ++f)
      af2[f] = *(const bf16x8*)&z_s[(f * 16 + fr) * 256 + (((kt * 4 + fq) ^ fr) * 8)];
#pragma unroll
    for (int f = 0; f < 4; ++f)
      bfr[f] = *(const bf16x8*)&Bst[cur * 8192 + (w * 64 + f * 16 + fr) * 32 + fsl];
#pragma unroll
    for (int fm = 0; fm < 2; ++fm)
#pragma unroll
      for (int fn = 0; fn < 4; ++fn)
        acc[fm][fn] = __builtin_amdgcn_mfma_f32_16x16x32_bf16(af2[fm], bfr[fn], acc[fm][fn], 0, 0, 0);
    vm_drain();
    __syncthreads();
  }
  float biasv[4];
#pragma unroll
  for (int fn = 0; fn < 4; ++fn) biasv[fn] = bout[w * 64 + fn * 16 + fr];
#pragma unroll
  for (int fm = 0; fm < 2; ++fm) {
#pragma unroll
    for (int fn = 0; fn < 4; ++fn) {
#pragma unroll
      for (int i = 0; i < 4; ++i) {
        const int row = fm * 16 + fq * 4 + i;  // 0..31
        const int col = w * 64 + fn * 16 + fr; // 0..255
        float v = fmaxf(acc[fm][fn][i] + biasv[fn], 0.0f);
        v += bf2f(x0b[(size_t)(r0 + row) * 256 + col]);
        out[(size_t)(r0 + row) * 256 + col] = v;
      }
    }
  }
}

// ---------------- host: launch -----------------------------------------------
extern "C" void kernel_launch(void* const* d_in, const int* in_sizes, int n_in,
                              void* d_out, int out_size, void* d_ws, size_t ws_size,
                              hipStream_t stream)
{
  const float* x    = (const float*)d_in[0];
  const float* np_  = (const float*)d_in[1];
  const float* Wh   = (const float*)d_in[2];
  const float* bh   = (const float*)d_in[3];
  const float* Wq   = (const float*)d_in[4];
  const float* bq   = (const float*)d_in[5];
  const float* Wk   = (const float*)d_in[6];
  const float* bk   = (const float*)d_in[7];
  const float* Wv   = (const float*)d_in[8];
  const float* bv   = (const float*)d_in[9];
  const float* Wout = (const float*)d_in[10];
  const float* bout = (const float*)d_in[11];
  const float* ln1g = (const float*)d_in[12];
  const float* ln1b = (const float*)d_in[13];
  const float* ln2g = (const float*)d_in[14];
  const float* ln2b = (const float*)d_in[15];
  const float* beta = (const float*)d_in[16];
  float* out = (float*)d_out;

  uintptr_t p = (uintptr_t)d_ws;
  ushort* x0b    = (ushort*)p; p += (size_t)65536 * 256 * 2;   // 33.5 MB
  ushort* hqkv   = (ushort*)p; p += (size_t)65536 * 1024 * 2;  // 134 MB
  ushort* zb     = (ushort*)p; p += (size_t)65536 * 256 * 2;   // (unused now)
  ushort* Wcat_t = (ushort*)p; p += (size_t)1024 * 256 * 2;
  ushort* Woutt  = (ushort*)p; p += (size_t)256 * 256 * 2;
  float*  bcat   = (float*)p;  p += (size_t)1024 * 4;
  float*  kv     = (float*)p;  p += (size_t)65536 * 4;
  float*  ksum   = (float*)p;  p += (size_t)2048 * 4;
  (void)zb;

  ln1_k<<<16384, 256, 0, stream>>>(x, ln1g, ln1b, x0b,
                                   Wh, Wq, Wk, Wv, Wout, bh, bq, bk, bv,
                                   Wcat_t, Woutt, bcat, kv, ksum);
  gemm_bf16_k<0><<<4096, 256, 0, stream>>>(x0b, Wcat_t, bcat, np_, nullptr, hqkv, nullptr);
  kvred_k<<<1024, 256, 0, stream>>>(hqkv, kv, ksum);
  attout_k<<<2048, 256, 0, stream>>>(hqkv, kv, ksum, ln2g, ln2b, beta,
                                     Woutt, bout, x0b, out);
}